// Round 2
// baseline (116226.770 us; speedup 1.0000x reference)
//
#include <hip/hip_runtime.h>

#define NB 32
#define TENC 300
#define TDEC 500
#define NMEL 80
#define ENCD 512
#define PRE 256
#define ADIM 128

// ---------------- workspace layout (float offsets) ----------------
#define OFF_DECINS 0ull                         // 500*32*256 = 4,096,000
#define OFF_H1M    4096000ull                   // 4,096,000 (prenet scratch; aliases GPA region, used only pre-loop)
#define OFF_GPA    4096000ull                   // 4*32*4096 = 524,288
#define OFF_GPD    (OFF_GPA + 524288ull)        // 524,288
#define OFF_E      (OFF_GPD + 524288ull)        // 9,600
#define OFF_PQ     (OFF_E + 9600ull)            // 4,096
#define OFF_PM     8192000ull                   // 32*300*128 = 1,228,800
#define OFF_STATE  (OFF_PM + 1228800ull)
#define OFF_AH0    (OFF_STATE + 0ull)
#define OFF_AH1    (OFF_STATE + 32768ull)
#define OFF_AC     (OFF_STATE + 65536ull)
#define OFF_DH0    (OFF_STATE + 98304ull)
#define OFF_DH1    (OFF_STATE + 131072ull)
#define OFF_DC     (OFF_STATE + 163840ull)
#define OFF_CTX    (OFF_STATE + 196608ull)      // 16,384
#define OFF_AW     (OFF_STATE + 212992ull)      // 9,600
#define OFF_AWC    (OFF_STATE + 222592ull)      // 9,600
#define STATE_N    232192ull
#define OFF_QWT    (OFF_STATE + STATE_N)        // 131,072
#define OFF_PROJWT (OFF_QWT + 131072ull)        // 122,880
#define OFF_MWT    (OFF_PROJWT + 122880ull)     // 65,536
#define OFF_W1T    (OFF_MWT + 65536ull)         // 20,480
#define OFF_W2T    (OFF_W1T + 20480ull)         // 65,536

// ---------------- threefry2x32 (matches JAX bit-exactly) ----------------
__host__ __device__ __forceinline__ unsigned rotl32(unsigned v, int r){ return (v<<r)|(v>>(32-r)); }

__host__ __device__ __forceinline__ void tf2x32(unsigned k0, unsigned k1, unsigned c0, unsigned c1,
                                                unsigned& y0, unsigned& y1){
  unsigned ks2 = k0 ^ k1 ^ 0x1BD11BDAu;
  unsigned x0 = c0 + k0, x1 = c1 + k1;
#define TFR(r) x0 += x1; x1 = rotl32(x1, r); x1 ^= x0;
  TFR(13) TFR(15) TFR(26) TFR(6)
  x0 += k1;  x1 += ks2 + 1u;
  TFR(17) TFR(29) TFR(16) TFR(24)
  x0 += ks2; x1 += k0 + 2u;
  TFR(13) TFR(15) TFR(26) TFR(6)
  x0 += k0;  x1 += k1 + 3u;
  TFR(17) TFR(29) TFR(16) TFR(24)
  x0 += k1;  x1 += ks2 + 4u;
  TFR(13) TFR(15) TFR(26) TFR(6)
  x0 += ks2; x1 += k0 + 5u;
#undef TFR
  y0 = x0; y1 = x1;
}

// Partitionable threefry random_bits (JAX >= 0.4.30 default):
// 32-bit bits for flat index i = y0 ^ y1 of threefry2x32(key, (i>>32, i&0xFFFFFFFF)).
// Our sizes < 2^32 so hi word = 0.
__device__ __forceinline__ float mask_scale(unsigned k0, unsigned k1, unsigned idx){
  unsigned y0, y1;
  tf2x32(k0, k1, 0u, idx, y0, y1);
  unsigned bits = y0 ^ y1;
  float u = __uint_as_float((bits >> 9) | 0x3f800000u) - 1.0f;
  return (u < 0.9f) ? (1.0f/0.9f) : 0.0f;
}

// ---------------- setup: zero states + weight transposes ----------------
__global__ __launch_bounds__(256) void k_setup(float* __restrict__ ws,
    const float* __restrict__ qW, const float* __restrict__ projW, const float* __restrict__ mW,
    const float* __restrict__ w1, const float* __restrict__ w2){
  long i = (long)blockIdx.x*256 + threadIdx.x;
  long stride = (long)gridDim.x*256;
  float* st = ws + OFF_STATE;
  for (long x = i; x < (long)STATE_N; x += stride) st[x] = 0.f;
  float* qWT = ws + OFF_QWT;     // [1024][128]
  for (long x = i; x < 1024*128; x += stride){ int u = x>>7, d = x&127; qWT[x] = qW[(size_t)d*1024+u]; }
  float* pWT = ws + OFF_PROJWT;  // [1536][80]
  for (long x = i; x < 1536*80; x += stride){ int k = x/80, m = x%80; pWT[x] = projW[(size_t)m*1536+k]; }
  float* mWT = ws + OFF_MWT;     // [512][128]
  for (long x = i; x < 512*128; x += stride){ int k = x>>7, d = x&127; mWT[x] = mW[(size_t)d*512+k]; }
  float* w1T = ws + OFF_W1T;     // [80][256]
  for (long x = i; x < 80*256; x += stride){ int m = x>>8, u = x&255; w1T[x] = w1[(size_t)u*80+m]; }
  float* w2T = ws + OFF_W2T;     // [256][256]
  for (long x = i; x < 256*256; x += stride){ int k = x>>8, u = x&255; w2T[x] = w2[(size_t)u*256+k]; }
}

// ---------------- prenet ----------------
__global__ __launch_bounds__(256) void k_prenet1(const float* __restrict__ di,
    const float* __restrict__ W1T, float* __restrict__ h1m, unsigned k10, unsigned k11){
  __shared__ float xs[NMEL];
  int bid = blockIdx.x;           // t*32 + b, t in [0,500)
  int t = bid >> 5, b = bid & 31;
  int tid = threadIdx.x;
  if (tid < NMEL) xs[tid] = (t == 0) ? 0.f : di[(size_t)b*40000 + (size_t)tid*500 + (t-1)];
  __syncthreads();
  float acc = 0.f;
  for (int m = 0; m < NMEL; ++m) acc += xs[m] * W1T[m*256 + tid];
  acc = fmaxf(acc, 0.f);
  unsigned idx = (unsigned)bid*256u + (unsigned)tid;
  h1m[(size_t)bid*256 + tid] = acc * mask_scale(k10, k11, idx);
}

__global__ __launch_bounds__(256) void k_prenet2(const float* __restrict__ h1m,
    const float* __restrict__ W2T, float* __restrict__ dec_ins, unsigned k20, unsigned k21){
  __shared__ float hs[PRE];
  int bid = blockIdx.x;
  int tid = threadIdx.x;
  hs[tid] = h1m[(size_t)bid*256 + tid];
  __syncthreads();
  float acc = 0.f;
  for (int k = 0; k < PRE; ++k) acc += hs[k] * W2T[k*256 + tid];
  acc = fmaxf(acc, 0.f);
  unsigned idx = (unsigned)bid*256u + (unsigned)tid;
  dec_ins[(size_t)bid*256 + tid] = acc * mask_scale(k20, k21, idx);
}

// ---------------- processed memory ----------------
__global__ __launch_bounds__(128) void k_procmem(const float* __restrict__ mem,
    const float* __restrict__ mWT, float* __restrict__ pm){
  __shared__ float ms[ENCD];
  int bid = blockIdx.x;  // b*300 + j
  int tid = threadIdx.x;
  const float* src = mem + (size_t)bid*ENCD;
  for (int i = tid; i < ENCD; i += 128) ms[i] = src[i];
  __syncthreads();
  float acc = 0.f;
  for (int k = 0; k < ENCD; ++k) acc += ms[k] * mWT[k*128 + tid];
  pm[(size_t)bid*128 + tid] = acc;
}

// ---------------- LSTM gate GEMM (K-split x4, partials) ----------------
// C[b,row] = sum_k X[b,k]*W[row,k];  X = [s0(l0) | s1(512) | hseg(1024)]
// W = [W1 (width l0+512) | W2 (width 1024)]
__global__ __launch_bounds__(256) void k_gemm(const float* __restrict__ W1, const float* __restrict__ W2,
    const float* __restrict__ s0, int l0, const float* __restrict__ s1, const float* __restrict__ hseg,
    int Ktot, float* __restrict__ gp){
  __shared__ float Xs[32][32];
  __shared__ float Ws[64][36];
  int rt = blockIdx.x & 63, ks = blockIdx.x >> 6;
  int tid = threadIdx.x;
  int rp = tid & 31, bq = tid >> 5;
  int xw = l0 + 512;
  int kr = Ktot >> 2;
  int kbeg = ks*kr, kend = kbeg + kr;
  int row0 = rt*64;
  float acc[2][4] = {};
  for (int kc = kbeg; kc < kend; kc += 32){
#pragma unroll
    for (int i = 0; i < 4; ++i){
      int flat = tid + i*256;
      int b = flat >> 5, kk = flat & 31;
      int k = kc + kk;
      float v;
      if (k < l0) v = s0[(size_t)b*l0 + k];
      else if (k < xw) v = s1[(b<<9) + (k - l0)];
      else v = hseg[(b<<10) + (k - xw)];
      Xs[b][kk] = v;
    }
#pragma unroll
    for (int i = 0; i < 8; ++i){
      int flat = tid + i*256;
      int r = flat >> 5, kk = flat & 31;
      int k = kc + kk;
      int row = row0 + r;
      Ws[r][kk] = (k < xw) ? W1[(size_t)row*xw + k] : W2[((size_t)row<<10) + (k - xw)];
    }
    __syncthreads();
#pragma unroll
    for (int kk = 0; kk < 32; kk += 4){
      float4 w0 = *(const float4*)&Ws[2*rp][kk];
      float4 w1 = *(const float4*)&Ws[2*rp+1][kk];
#pragma unroll
      for (int j = 0; j < 4; ++j){
        float4 xv = *(const float4*)&Xs[bq + 8*j][kk];
        acc[0][j] += w0.x*xv.x; acc[0][j] += w0.y*xv.y; acc[0][j] += w0.z*xv.z; acc[0][j] += w0.w*xv.w;
        acc[1][j] += w1.x*xv.x; acc[1][j] += w1.y*xv.y; acc[1][j] += w1.z*xv.z; acc[1][j] += w1.w*xv.w;
      }
    }
    __syncthreads();
  }
#pragma unroll
  for (int rr = 0; rr < 2; ++rr)
#pragma unroll
    for (int j = 0; j < 4; ++j){
      int b = bq + 8*j;
      gp[((size_t)(ks*32 + b))*4096 + row0 + 2*rp + rr] = acc[rr][j];
    }
}

// ---------------- shared LSTM epilogue (per-b block, 256 thr, 4 units/thr) ----------------
__device__ __forceinline__ void lstm_update4(const float* __restrict__ gp, const float* __restrict__ bih,
    const float* __restrict__ bhh, float* __restrict__ c_io, float* __restrict__ h_out,
    float* __restrict__ sH, int b, int tid){
  int u0 = tid*4;
  float gs[4][4];
#pragma unroll
  for (int g = 0; g < 4; ++g){
    float4 s  = *(const float4*)&bih[g*1024 + u0];
    float4 s2 = *(const float4*)&bhh[g*1024 + u0];
    float a0 = s.x + s2.x, a1 = s.y + s2.y, a2 = s.z + s2.z, a3 = s.w + s2.w;
    const float* base = gp + (size_t)b*4096 + g*1024 + u0;
#pragma unroll
    for (int ks = 0; ks < 4; ++ks){
      float4 p = *(const float4*)(base + (size_t)ks*131072);
      a0 += p.x; a1 += p.y; a2 += p.z; a3 += p.w;
    }
    gs[g][0]=a0; gs[g][1]=a1; gs[g][2]=a2; gs[g][3]=a3;
  }
  float4 c4 = *(const float4*)&c_io[b*1024 + u0];
  float cold[4] = {c4.x, c4.y, c4.z, c4.w};
  float cn[4], hn[4];
#pragma unroll
  for (int e = 0; e < 4; ++e){
    float ii = 1.f/(1.f + expf(-gs[0][e]));
    float ff = 1.f/(1.f + expf(-gs[1][e]));
    float gg = tanhf(gs[2][e]);
    float oo = 1.f/(1.f + expf(-gs[3][e]));
    float c = ff*cold[e] + ii*gg;
    cn[e] = c; hn[e] = oo*tanhf(c);
  }
  *(float4*)&c_io[b*1024 + u0]  = make_float4(cn[0],cn[1],cn[2],cn[3]);
  *(float4*)&h_out[b*1024 + u0] = make_float4(hn[0],hn[1],hn[2],hn[3]);
  sH[u0]=hn[0]; sH[u0+1]=hn[1]; sH[u0+2]=hn[2]; sH[u0+3]=hn[3];
}

// att update: LSTM + pq = ah @ q_W^T (via transposed qWT)
__global__ __launch_bounds__(256) void k_att_update(const float* __restrict__ gp,
    const float* __restrict__ bih, const float* __restrict__ bhh,
    float* __restrict__ ac, float* __restrict__ h_out,
    const float* __restrict__ qWT, float* __restrict__ pq){
  __shared__ float sAh[1024];
  __shared__ float pqs[256];
  int b = blockIdx.x, tid = threadIdx.x;
  lstm_update4(gp, bih, bhh, ac, h_out, sAh, b, tid);
  __syncthreads();
  int d = tid & 127, half = tid >> 7;
  const float* qt = qWT + (size_t)(half*512)*128 + d;
  float acc = 0.f;
  for (int u = 0; u < 512; ++u) acc += sAh[half*512 + u] * qt[(size_t)u*128];
  pqs[half*128 + d] = acc;
  __syncthreads();
  if (tid < 128) pq[b*128 + tid] = pqs[tid] + pqs[128 + tid];
}

// ---------------- energy: conv + dense + tanh + v dot  (block = (b, j-tile of 16)) ----------------
__global__ __launch_bounds__(256) void k_energy(const float* __restrict__ aw, const float* __restrict__ awc,
    const float* __restrict__ lcW, const float* __restrict__ ldW, const float* __restrict__ vw,
    const float* __restrict__ pq, const float* __restrict__ pm, float* __restrict__ e_ws){
  int bb = blockIdx.x;
  int b = bb & 31, jt = bb >> 5;
  int j0 = jt*16;
  int tid = threadIdx.x;
  __shared__ float sIn[2][46];
  __shared__ float cfs[16][33];
  __shared__ float ep[16][17];
  __shared__ float sPq[128];
  if (tid < 46){ int j = j0 - 15 + tid; sIn[0][tid] = (j >= 0 && j < 300) ? aw[b*300 + j] : 0.f; }
  else if (tid < 92){ int i = tid - 46; int j = j0 - 15 + i; sIn[1][i] = (j >= 0 && j < 300) ? awc[b*300 + j] : 0.f; }
  if (tid >= 128) sPq[tid - 128] = pq[b*128 + (tid - 128)];
  __syncthreads();
  { // conv: thread (fg=tid&15 -> f pair, jl=tid>>4)
    int fg = tid & 15, jl = tid >> 4;
    int f0 = 2*fg;
    float c0 = 0.f, c1 = 0.f;
#pragma unroll
    for (int c = 0; c < 2; ++c)
#pragma unroll
      for (int k = 0; k < 31; ++k){
        float a = sIn[c][jl + k];
        c0 += a * lcW[f0*62 + c*31 + k];
        c1 += a * lcW[(f0+1)*62 + c*31 + k];
      }
    cfs[jl][f0] = c0; cfs[jl][f0+1] = c1;
  }
  __syncthreads();
  { // dense + tanh + v: thread (dg=tid&15 -> 8 d's, jl=tid>>4)
    int dg = tid & 15, jl = tid >> 4;
    int j = j0 + jl;
    float s = 0.f;
    if (j < 300){
      const float* pmrow = pm + ((size_t)(b*300 + j))*128 + dg*8;
#pragma unroll
      for (int dd = 0; dd < 8; ++dd){
        int d = dg*8 + dd;
        float acc = sPq[d] + pmrow[dd];
#pragma unroll
        for (int f = 0; f < 32; ++f) acc += cfs[jl][f] * ldW[d*32 + f];
        s += vw[d] * tanhf(acc);
      }
    }
    ep[jl][dg] = s;
  }
  __syncthreads();
  if (tid < 16){
    int j = j0 + tid;
    if (j < 300){
      float s = 0.f;
#pragma unroll
      for (int dg = 0; dg < 16; ++dg) s += ep[tid][dg];
      e_ws[b*300 + j] = s;
    }
  }
}

// ---------------- softmax + context + cumulative + alignment out (block = b) ----------------
__global__ __launch_bounds__(256) void k_soft(const float* __restrict__ e_ws, const int* __restrict__ lens,
    const float* __restrict__ mem, float* __restrict__ aw, float* __restrict__ awc, float* __restrict__ ctx,
    float* __restrict__ out, int t){
  int b = blockIdx.x, tid = threadIdx.x;
  __shared__ float se[300];
  __shared__ float sa[300];
  __shared__ float red[256];
  int len = lens[b];
  for (int j = tid; j < 300; j += 256) se[j] = e_ws[b*300 + j];
  __syncthreads();
  float m = -1e30f;
  for (int j = tid; j < len; j += 256) m = fmaxf(m, se[j]);
  red[tid] = m; __syncthreads();
  for (int s = 128; s > 0; s >>= 1){ if (tid < s) red[tid] = fmaxf(red[tid], red[tid + s]); __syncthreads(); }
  float mx = red[0]; __syncthreads();
  float ss = 0.f;
  for (int j = tid; j < len; j += 256) ss += expf(se[j] - mx);
  red[tid] = ss; __syncthreads();
  for (int s = 128; s > 0; s >>= 1){ if (tid < s) red[tid] += red[tid + s]; __syncthreads(); }
  float inv = 1.f/red[0];
  float* al = out + 1296000 + (size_t)b*150000 + (size_t)t*300;
  for (int j = tid; j < 300; j += 256){
    float v = (j < len) ? expf(se[j] - mx)*inv : 0.f;
    sa[j] = v;
    aw[b*300 + j] = v;
    awc[b*300 + j] += v;
    al[j] = v;
  }
  __syncthreads();
  const float* mb = mem + (size_t)b*300*512;
  for (int d = tid; d < 512; d += 256){
    float acc = 0.f;
    for (int j = 0; j < len; ++j) acc += sa[j]*mb[(size_t)j*512 + d];
    ctx[b*512 + d] = acc;
  }
}

// ---------------- dec update: LSTM + mel + gate outputs ----------------
__global__ __launch_bounds__(256) void k_dec_update(const float* __restrict__ gp,
    const float* __restrict__ bih, const float* __restrict__ bhh,
    float* __restrict__ dc, float* __restrict__ dh_out, const float* __restrict__ ctx,
    const float* __restrict__ pWT, const float* __restrict__ projb,
    const float* __restrict__ gateW, const float* __restrict__ gateb,
    float* __restrict__ out, int t){
  __shared__ float sDh[1024];
  __shared__ float sCtx[512];
  __shared__ float red[256];
  __shared__ float melp[3][80];
  int b = blockIdx.x, tid = threadIdx.x;
  lstm_update4(gp, bih, bhh, dc, dh_out, sDh, b, tid);
  for (int i = tid; i < 512; i += 256) sCtx[i] = ctx[b*512 + i];
  __syncthreads();
  if (tid < 240){
    int m = tid % 80, seg = tid / 80;
    float mp = 0.f;
    for (int k = seg*512; k < seg*512 + 512; ++k){
      float x = (k < 1024) ? sDh[k] : sCtx[k - 1024];
      mp += x * pWT[(size_t)k*80 + m];
    }
    melp[seg][m] = mp;
  }
  float g = 0.f;
  for (int k = tid; k < 1536; k += 256){
    float x = (k < 1024) ? sDh[k] : sCtx[k - 1024];
    g += x * gateW[k];
  }
  red[tid] = g; __syncthreads();
  for (int s = 128; s > 0; s >>= 1){ if (tid < s) red[tid] += red[tid + s]; __syncthreads(); }
  if (tid == 0) out[1280000 + (size_t)b*500 + t] = red[0] + gateb[0];
  if (tid < 80){
    float mel = melp[0][tid] + melp[1][tid] + melp[2][tid] + projb[tid];
    out[(size_t)b*40000 + (size_t)tid*500 + t] = mel;
  }
}

// ---------------- host ----------------
extern "C" void kernel_launch(void* const* d_in, const int* in_sizes, int n_in,
                              void* d_out, int out_size, void* d_ws, size_t ws_size,
                              hipStream_t stream) {
  const float* memory   = (const float*)d_in[0];
  const float* dec_in   = (const float*)d_in[1];
  const int*   lens     = (const int*)  d_in[2];
  const float* pre_W1   = (const float*)d_in[3];
  const float* pre_W2   = (const float*)d_in[4];
  const float* att_Wih  = (const float*)d_in[5];
  const float* att_Whh  = (const float*)d_in[6];
  const float* att_bih  = (const float*)d_in[7];
  const float* att_bhh  = (const float*)d_in[8];
  const float* q_W      = (const float*)d_in[9];
  const float* m_W      = (const float*)d_in[10];
  const float* v_w      = (const float*)d_in[11];
  const float* lc_W     = (const float*)d_in[12];
  const float* ld_W     = (const float*)d_in[13];
  const float* dec_Wih  = (const float*)d_in[14];
  const float* dec_Whh  = (const float*)d_in[15];
  const float* dec_bih  = (const float*)d_in[16];
  const float* dec_bhh  = (const float*)d_in[17];
  const float* proj_W   = (const float*)d_in[18];
  const float* proj_b   = (const float*)d_in[19];
  const float* gate_W   = (const float*)d_in[20];
  const float* gate_b   = (const float*)d_in[21];
  float* out = (float*)d_out;
  float* ws  = (float*)d_ws;

  // Partitionable (foldlike) split of jax.random.key(1):
  // subkey i = threefry2x32(key=(0,1), counts=(hi=0, lo=i)); both words form the key.
  unsigned k10, k11, k20, k21;
  tf2x32(0u, 1u, 0u, 0u, k10, k11);   // first split key  (layer-1 dropout)
  tf2x32(0u, 1u, 0u, 1u, k20, k21);   // second split key (layer-2 dropout)

  k_setup<<<1024, 256, 0, stream>>>(ws, q_W, proj_W, m_W, pre_W1, pre_W2);
  k_prenet1<<<TDEC*NB, 256, 0, stream>>>(dec_in, ws + OFF_W1T, ws + OFF_H1M, k10, k11);
  k_prenet2<<<TDEC*NB, 256, 0, stream>>>(ws + OFF_H1M, ws + OFF_W2T, ws + OFF_DECINS, k20, k21);
  k_procmem<<<NB*TENC, 128, 0, stream>>>(memory, ws + OFF_MWT, ws + OFF_PM);

  float* AH[2] = { ws + OFF_AH0, ws + OFF_AH1 };
  float* DH[2] = { ws + OFF_DH0, ws + OFF_DH1 };

  for (int t = 0; t < TDEC; ++t){
    // attention LSTM: X = [dec_ins(t) (256) | ctx (512)], H = ah_old (1024)
    k_gemm<<<256, 256, 0, stream>>>(att_Wih, att_Whh,
        ws + OFF_DECINS + (size_t)t*NB*PRE, PRE, ws + OFF_CTX, AH[t & 1], 1792, ws + OFF_GPA);
    k_att_update<<<NB, 256, 0, stream>>>(ws + OFF_GPA, att_bih, att_bhh,
        ws + OFF_AC, AH[(t + 1) & 1], ws + OFF_QWT, ws + OFF_PQ);
    k_energy<<<NB*19, 256, 0, stream>>>(ws + OFF_AW, ws + OFF_AWC, lc_W, ld_W, v_w,
        ws + OFF_PQ, ws + OFF_PM, ws + OFF_E);
    k_soft<<<NB, 256, 0, stream>>>(ws + OFF_E, lens, memory,
        ws + OFF_AW, ws + OFF_AWC, ws + OFF_CTX, out, t);
    // decoder LSTM: X = [ah_new (1024) | ctx (512)], H = dh_old
    k_gemm<<<256, 256, 0, stream>>>(dec_Wih, dec_Whh,
        AH[(t + 1) & 1], 1024, ws + OFF_CTX, DH[t & 1], 2560, ws + OFF_GPD);
    k_dec_update<<<NB, 256, 0, stream>>>(ws + OFF_GPD, dec_bih, dec_bhh,
        ws + OFF_DC, DH[(t + 1) & 1], ws + OFF_CTX,
        ws + OFF_PROJWT, proj_b, gate_W, gate_b, out, t);
  }
}